// Round 1
// baseline (654.140 us; speedup 1.0000x reference)
//
#include <hip/hip_runtime.h>
#include <hip/hip_bf16.h>

// ---------------------------------------------------------------------------
// TileSelfAttention: x(32768x1024) -> K,Q,V = x@W.T+b (each 32768x512)
//   aw[b,t,s] = sum_c K[b,t,c]*Q[b,s,c] / sqrt(512)   (b=512, t,s=64)
//   aw = softmax over BATCH axis (axis=0)
//   out[b,c,s] = sum_t V[b,t,c]*aw[b,t,s]             (out: 512 x 512 x 64 fp32)
//
// Precision strategy: threshold ~1.1e-3 (= absmax_ref * 2^-10) is tighter than
// plain-bf16 GEMM noise. Use Dekker split x = hi + lo (bf16 each, ~17-bit
// mantissa combined); compute x@W.T as hi*hi + hi*lo + lo*hi via one bf16 MFMA
// GEMM with K' = 3*1024, switching operand pointers per 1024-col segment.
// Small einsums + softmax stay fp32 VALU (only ~4.3 GF).
// ---------------------------------------------------------------------------

typedef __bf16 bf16;
using bf16x4 = __attribute__((ext_vector_type(4))) __bf16;
using bf16x8 = __attribute__((ext_vector_type(8))) __bf16;
using f32x4  = __attribute__((ext_vector_type(4))) float;

#define M_ROWS 32768
#define CIN    1024
#define COUT   512
#define NT     64
#define BATCH  512

// workspace byte offsets (total ~350.2 MB)
#define OFF_XHI 0ul
#define OFF_XLO 67108864ul
#define OFF_WSP 134217728ul   // 3 proj * (hi 524288 + lo 524288) bf16 elems
#define OFF_K   140509184ul
#define OFF_Q   207618048ul
#define OFF_V   274726912ul
#define OFF_AW  341835776ul

// ---------------------------------------------------------------------------
// split: fp32 -> (hi, lo) bf16 arrays (flat). Vectorized float4 / bf16x4.
// ---------------------------------------------------------------------------
__global__ void split_kernel(const float* __restrict__ x, bf16* __restrict__ hi,
                             bf16* __restrict__ lo, int n4) {
  int i = blockIdx.x * blockDim.x + threadIdx.x;
  int stride = gridDim.x * blockDim.x;
  for (; i < n4; i += stride) {
    float4 v = ((const float4*)x)[i];
    bf16 h0 = (bf16)v.x, h1 = (bf16)v.y, h2 = (bf16)v.z, h3 = (bf16)v.w;
    bf16 l0 = (bf16)(v.x - (float)h0);
    bf16 l1 = (bf16)(v.y - (float)h1);
    bf16 l2 = (bf16)(v.z - (float)h2);
    bf16 l3 = (bf16)(v.w - (float)h3);
    ((bf16x4*)hi)[i] = bf16x4{h0, h1, h2, h3};
    ((bf16x4*)lo)[i] = bf16x4{l0, l1, l2, l3};
  }
}

// ---------------------------------------------------------------------------
// GEMM: P[m,n] = sum_k' A[m,k']*B[n,k'] + bias[n], K'=3072 (3 segments).
// m97 structure: 128x128 tile, BK=32, 4 waves (2x2), 16x16x32 bf16 MFMA,
// global_load_lds width 16, 2-barrier K loop. N=1536 (3 projections of 512).
// ---------------------------------------------------------------------------
__device__ __forceinline__ void gl_lds16(const bf16* g, bf16* l) {
  __builtin_amdgcn_global_load_lds(
      (const __attribute__((address_space(1))) unsigned int*)g,
      (__attribute__((address_space(3))) unsigned int*)l, 16, 0, 0);
}

__global__ __launch_bounds__(256) void gemm_kqv(
    const bf16* __restrict__ Xhi, const bf16* __restrict__ Xlo,
    const bf16* __restrict__ WB,   // [proj][hi|lo][512][1024]
    const float* __restrict__ bk, const float* __restrict__ bq,
    const float* __restrict__ bv,
    float* __restrict__ K, float* __restrict__ Q, float* __restrict__ V) {
  __shared__ bf16 As[128 * 32];
  __shared__ bf16 Bs[128 * 32];

  const int bid = blockIdx.x;          // 3072 = 256 * 12
  const int bm = bid / 12;
  const int bn = bid % 12;
  const int gm0 = bm * 128;
  const int proj = bn >> 2;            // 0:K 1:Q 2:V
  const int wrow0 = (bn & 3) * 128;    // row within the 512-row W matrix

  const int t = threadIdx.x;
  const int lane = t & 63;
  const int w = t >> 6;
  const int wr = w >> 1, wc = w & 1;
  const int lr = lane & 15;            // frag row/col
  const int lk = lane >> 4;            // frag k-group

  const int arow = t >> 2;             // staging row 0..63 (call0), +64 (call1)
  const int ak8 = (t & 3) << 3;        // k element offset (8 bf16 = 16B)

  const bf16* Wproj = WB + (size_t)proj * 1048576ul;

  f32x4 acc[4][4] = {};

  for (int kb = 0; kb < 96; ++kb) {
    const int seg = kb >> 5;                 // 0: hi*hi  1: hi*lo  2: lo*hi
    const int kin = (kb & 31) * 32;
    const bf16* Aseg = (seg == 2) ? Xlo : Xhi;
    const bf16* Bseg = Wproj + (seg == 1 ? 524288 : 0);

    const bf16* ga = Aseg + (size_t)(gm0 + arow) * 1024 + kin + ak8;
    gl_lds16(ga, As + t * 8);
    gl_lds16(ga + 64 * 1024, As + 2048 + t * 8);
    const bf16* gb = Bseg + (size_t)(wrow0 + arow) * 1024 + kin + ak8;
    gl_lds16(gb, Bs + t * 8);
    gl_lds16(gb + 64 * 1024, Bs + 2048 + t * 8);

    __syncthreads();   // drains vmcnt -> staging visible

    bf16x8 af[4], bfr[4];
#pragma unroll
    for (int i = 0; i < 4; ++i)
      af[i] = *(const bf16x8*)(As + ((wr * 64 + i * 16 + lr) * 32 + lk * 8));
#pragma unroll
    for (int j = 0; j < 4; ++j)
      bfr[j] = *(const bf16x8*)(Bs + ((wc * 64 + j * 16 + lr) * 32 + lk * 8));

#pragma unroll
    for (int i = 0; i < 4; ++i)
#pragma unroll
      for (int j = 0; j < 4; ++j)
        acc[i][j] = __builtin_amdgcn_mfma_f32_16x16x32_bf16(af[i], bfr[j],
                                                            acc[i][j], 0, 0, 0);

    __syncthreads();   // all reads done before next stage overwrites
  }

  const float* bias = (proj == 0) ? bk : (proj == 1 ? bq : bv);
  float* Out = (proj == 0) ? K : (proj == 1 ? Q : V);
  const int cbase = (bn & 3) * 128 + wc * 64;
#pragma unroll
  for (int j = 0; j < 4; ++j) {
    const int c = cbase + j * 16 + lr;       // C/D: col = lane&15
    const float bb = bias[c];
#pragma unroll
    for (int i = 0; i < 4; ++i) {
      const int row0 = gm0 + wr * 64 + i * 16 + lk * 4;  // row=(lane>>4)*4+reg
#pragma unroll
      for (int r = 0; r < 4; ++r)
        Out[(size_t)(row0 + r) * 512 + c] = acc[i][j][r] + bb;
    }
  }
}

// ---------------------------------------------------------------------------
// logits: AW[b,t,s] = (1/sqrt(512)) * sum_c K[b*64+t,c] * Q[b*64+s,c]
// one block per batch; c-chunks of 64 staged TRANSPOSED ([cc][row], pad 65)
// so inner reads are broadcast/2-way conflict free. 4x4 outputs per thread.
// ---------------------------------------------------------------------------
__global__ __launch_bounds__(256) void logits_kernel(
    const float* __restrict__ K, const float* __restrict__ Q,
    float* __restrict__ AW) {
  __shared__ float Ks[64][65];  // [cc][t]
  __shared__ float Qs[64][65];  // [cc][s]
  const int b = blockIdx.x;
  const float* Kb = K + (size_t)b * 32768;
  const float* Qb = Q + (size_t)b * 32768;
  const int tid = threadIdx.x;
  const int tr = tid >> 4, tc = tid & 15;

  float acc[4][4] = {};
  for (int c0 = 0; c0 < 512; c0 += 64) {
    __syncthreads();
#pragma unroll
    for (int i = 0; i < 4; ++i) {
      int idx = tid + i * 256;       // 0..1023 float4 units
      int row = idx >> 4;            // 16 float4 per row
      int c4 = (idx & 15) * 4;
      float4 kv = *(const float4*)&Kb[row * 512 + c0 + c4];
      float4 qv = *(const float4*)&Qb[row * 512 + c0 + c4];
      Ks[c4 + 0][row] = kv.x; Ks[c4 + 1][row] = kv.y;
      Ks[c4 + 2][row] = kv.z; Ks[c4 + 3][row] = kv.w;
      Qs[c4 + 0][row] = qv.x; Qs[c4 + 1][row] = qv.y;
      Qs[c4 + 2][row] = qv.z; Qs[c4 + 3][row] = qv.w;
    }
    __syncthreads();
#pragma unroll 4
    for (int cc = 0; cc < 64; ++cc) {
      float kx[4], qx[4];
#pragma unroll
      for (int r = 0; r < 4; ++r) kx[r] = Ks[cc][tr * 4 + r];
#pragma unroll
      for (int r = 0; r < 4; ++r) qx[r] = Qs[cc][tc * 4 + r];
#pragma unroll
      for (int i = 0; i < 4; ++i)
#pragma unroll
        for (int j = 0; j < 4; ++j) acc[i][j] += kx[i] * qx[j];
    }
  }
  const float scale = 0.04419417382415922f;  // 1/sqrt(512)
#pragma unroll
  for (int i = 0; i < 4; ++i)
#pragma unroll
    for (int j = 0; j < 4; ++j)
      AW[(size_t)b * 4096 + (tr * 4 + i) * 64 + (tc * 4 + j)] =
          acc[i][j] * scale;
}

// ---------------------------------------------------------------------------
// softmax over batch axis: for each (t,s), softmax across b=512.
// block per t (64 blocks), 256 threads = (s 0..63) x (b-quarter 0..3).
// ---------------------------------------------------------------------------
__global__ __launch_bounds__(256) void softmax_kernel(float* __restrict__ AW) {
  __shared__ float red[4][64];
  const int tt = blockIdx.x;          // tile index t
  const int tid = threadIdx.x;
  const int s = tid & 63, bq = tid >> 6;
  const size_t base = (size_t)tt * 64 + s;

  float m = -3.4e38f;
  for (int b = bq * 128; b < bq * 128 + 128; ++b)
    m = fmaxf(m, AW[(size_t)b * 4096 + base]);
  red[bq][s] = m;
  __syncthreads();
  m = fmaxf(fmaxf(red[0][s], red[1][s]), fmaxf(red[2][s], red[3][s]));
  __syncthreads();

  float sum = 0.f;
  for (int b = bq * 128; b < bq * 128 + 128; ++b)
    sum += __expf(AW[(size_t)b * 4096 + base] - m);
  red[bq][s] = sum;
  __syncthreads();
  sum = red[0][s] + red[1][s] + red[2][s] + red[3][s];
  const float inv = 1.0f / sum;

  for (int b = bq * 128; b < bq * 128 + 128; ++b) {
    size_t o = (size_t)b * 4096 + base;
    AW[o] = __expf(AW[o] - m) * inv;
  }
}

// ---------------------------------------------------------------------------
// out[b,c,s] = sum_t V[b*64+t, c] * P[b,t,s].  Block per batch; P in LDS;
// V read as wave-uniform float4 (L1/L2 served); lanes = s (coalesced stores).
// ---------------------------------------------------------------------------
__global__ __launch_bounds__(256) void out_kernel(
    const float* __restrict__ V, const float* __restrict__ AW,
    float* __restrict__ out) {
  __shared__ float Ps[64][65];
  const int b = blockIdx.x;
  const int tid = threadIdx.x;
  const float* Pb = AW + (size_t)b * 4096;
  for (int i = tid; i < 4096; i += 256) Ps[i >> 6][i & 63] = Pb[i];
  __syncthreads();

  const int s = tid & 63, cw = tid >> 6;  // wave id -> c group
  const float* Vb = V + (size_t)b * 32768;
  float* Ob = out + (size_t)b * 32768;

  for (int c0 = cw * 4; c0 < 512; c0 += 16) {
    float a0 = 0.f, a1 = 0.f, a2 = 0.f, a3 = 0.f;
#pragma unroll 8
    for (int tt = 0; tt < 64; ++tt) {
      float4 v = *(const float4*)&Vb[(size_t)tt * 512 + c0];
      float p = Ps[tt][s];
      a0 += v.x * p; a1 += v.y * p; a2 += v.z * p; a3 += v.w * p;
    }
    Ob[(size_t)(c0 + 0) * 64 + s] = a0;
    Ob[(size_t)(c0 + 1) * 64 + s] = a1;
    Ob[(size_t)(c0 + 2) * 64 + s] = a2;
    Ob[(size_t)(c0 + 3) * 64 + s] = a3;
  }
}

// ---------------------------------------------------------------------------
extern "C" void kernel_launch(void* const* d_in, const int* in_sizes, int n_in,
                              void* d_out, int out_size, void* d_ws,
                              size_t ws_size, hipStream_t stream) {
  const float* x  = (const float*)d_in[0];
  const float* Wk = (const float*)d_in[1];
  const float* bk = (const float*)d_in[2];
  const float* Wq = (const float*)d_in[3];
  const float* bq = (const float*)d_in[4];
  const float* Wv = (const float*)d_in[5];
  const float* bv = (const float*)d_in[6];
  float* out = (float*)d_out;

  char* ws = (char*)d_ws;   // needs ~350.3 MB
  bf16* Xhi = (bf16*)(ws + OFF_XHI);
  bf16* Xlo = (bf16*)(ws + OFF_XLO);
  bf16* WB  = (bf16*)(ws + OFF_WSP);
  float* K  = (float*)(ws + OFF_K);
  float* Q  = (float*)(ws + OFF_Q);
  float* V  = (float*)(ws + OFF_V);
  float* AW = (float*)(ws + OFF_AW);

  // 1) Dekker splits
  split_kernel<<<2048, 256, 0, stream>>>(x, Xhi, Xlo, 33554432 / 4);
  split_kernel<<<256, 256, 0, stream>>>(Wk, WB + 0ul * 1048576ul,
                                        WB + 0ul * 1048576ul + 524288ul,
                                        524288 / 4);
  split_kernel<<<256, 256, 0, stream>>>(Wq, WB + 1ul * 1048576ul,
                                        WB + 1ul * 1048576ul + 524288ul,
                                        524288 / 4);
  split_kernel<<<256, 256, 0, stream>>>(Wv, WB + 2ul * 1048576ul,
                                        WB + 2ul * 1048576ul + 524288ul,
                                        524288 / 4);

  // 2) QKV projections (compensated bf16 MFMA GEMM, K'=3072)
  gemm_kqv<<<3072, 256, 0, stream>>>(Xhi, Xlo, WB, bk, bq, bv, K, Q, V);

  // 3) logits
  logits_kernel<<<BATCH, 256, 0, stream>>>(K, Q, AW);

  // 4) softmax over batch axis
  softmax_kernel<<<NT, 256, 0, stream>>>(AW);

  // 5) output einsum
  out_kernel<<<BATCH, 256, 0, stream>>>(V, AW, out);
}

// Round 2
// 466.198 us; speedup vs baseline: 1.4031x; 1.4031x over previous
//
#include <hip/hip_runtime.h>
#include <hip/hip_bf16.h>

// ---------------------------------------------------------------------------
// TileSelfAttention, round 2.
// GEMM: 256x256 8-phase template (T1+T2+T3+T4+T5), compensated bf16 split,
//       K' = 3*1024 (hi*hi, hi*lo, lo*hi), seg-fastest K order for L2 reuse.
// out/logits: LDS-staged fp32 VALU, conflict-aware padding.
// ---------------------------------------------------------------------------

typedef __bf16 bf16;
using bf16x4 = __attribute__((ext_vector_type(4))) __bf16;
using bf16x8 = __attribute__((ext_vector_type(8))) __bf16;
using f32x4  = __attribute__((ext_vector_type(4))) float;

#define NT     64
#define BATCH  512

// workspace byte offsets (total ~350.2 MB)
#define OFF_XHI 0ul
#define OFF_XLO 67108864ul
#define OFF_WSP 134217728ul
#define OFF_K   140509184ul
#define OFF_Q   207618048ul
#define OFF_V   274726912ul
#define OFF_AW  341835776ul

// ---------------------------------------------------------------------------
__global__ void split_kernel(const float* __restrict__ x, bf16* __restrict__ hi,
                             bf16* __restrict__ lo, int n4) {
  int i = blockIdx.x * blockDim.x + threadIdx.x;
  int stride = gridDim.x * blockDim.x;
  for (; i < n4; i += stride) {
    float4 v = ((const float4*)x)[i];
    bf16 h0 = (bf16)v.x, h1 = (bf16)v.y, h2 = (bf16)v.z, h3 = (bf16)v.w;
    bf16 l0 = (bf16)(v.x - (float)h0);
    bf16 l1 = (bf16)(v.y - (float)h1);
    bf16 l2 = (bf16)(v.z - (float)h2);
    bf16 l3 = (bf16)(v.w - (float)h3);
    ((bf16x4*)hi)[i] = bf16x4{h0, h1, h2, h3};
    ((bf16x4*)lo)[i] = bf16x4{l0, l1, l2, l3};
  }
}

// ---------------------------------------------------------------------------
// 8-phase 256x256 GEMM.  A = X (32768 x 1024, hi/lo), B = W (rows = out cols).
// K-tiles kt = 0..47: seg = kt%3 (0:hi*hi 1:hi*lo 2:lo*hi), kc = kt/3.
// LDS (bf16 elems): buf c*32768 | A: +h*8192 | B: +16384+nh*8192.
// Swizzle: LDS[row][slot'] holds global slot s = slot'^(row&7) (involution).
// ---------------------------------------------------------------------------
__device__ __forceinline__ void gl_lds16(const bf16* g, bf16* l) {
  __builtin_amdgcn_global_load_lds(
      (const __attribute__((address_space(1))) unsigned int*)g,
      (__attribute__((address_space(3))) unsigned int*)l, 16, 0, 0);
}

#define VMCNT(n) asm volatile("s_waitcnt vmcnt(" #n ")" ::: "memory")
#define LGKM0    asm volatile("s_waitcnt lgkmcnt(0)" ::: "memory")

__global__ __launch_bounds__(512, 2) void gemm_kqv8(
    const bf16* __restrict__ Xhi, const bf16* __restrict__ Xlo,
    const bf16* __restrict__ WB,
    const float* __restrict__ bk, const float* __restrict__ bq,
    const float* __restrict__ bv,
    float* __restrict__ K, float* __restrict__ Q, float* __restrict__ V) {
  __shared__ __align__(16) bf16 lds[65536];  // 128 KiB

  // T1: bijective XCD swizzle (768 % 8 == 0 -> simple chunked form)
  const int bid = (blockIdx.x & 7) * 96 + (blockIdx.x >> 3);
  const int mt = bid / 6, nt = bid % 6;     // mt-major: 6 blocks share A-panel
  const int gm0 = mt * 256;
  const int proj = nt >> 1;
  const int wn0 = (nt & 1) * 256;

  const int tid = threadIdx.x;
  const int l = tid & 63;
  const int w = tid >> 6;
  const int wr = w >> 2, wc = w & 3;        // 2M x 4N waves
  const int lr = l & 15, lk = l >> 4;
  const int x = lr & 7;
  const int slot0 = (lk ^ x) * 8;           // kh=0 slot (elems); kh=1 = ^32

  const bf16* Ahi = Xhi + (size_t)gm0 * 1024;
  const bf16* Alo = Xlo + (size_t)gm0 * 1024;
  const bf16* Whi = WB + (size_t)proj * 1048576ul + (size_t)wn0 * 1024;
  const bf16* Wlo = Whi + 524288;

  // staging per-lane constants: row = srow + j*8, global col-slot pre-swizzled
  const int srow = w * 16 + (l >> 3);
  const int scol = ((l & 7) ^ (l >> 3)) * 8;
  const int sdst = w * 1024 + l * 8;

  f32x4 acc[8][4] = {};
  bf16x8 aF[4][2];
  bf16x8 bF[2][2][2];  // [nh][nf2][kh]

  auto STAGE = [&](const bf16* gb, int de) {
    gl_lds16(gb + (size_t)srow * 1024 + scol, lds + de + sdst);
    gl_lds16(gb + (size_t)(srow + 8) * 1024 + scol, lds + de + 512 + sdst);
  };
  auto READ_A = [&](int cb, int h) {
#pragma unroll
    for (int mf = 0; mf < 4; ++mf) {
      const bf16* p = lds + cb + h * 8192 + (wr * 64 + mf * 16 + lr) * 64;
      aF[mf][0] = *(const bf16x8*)(p + slot0);
      aF[mf][1] = *(const bf16x8*)(p + (slot0 ^ 32));
    }
  };
  auto READ_B = [&](int cb, int nh) {
#pragma unroll
    for (int nf = 0; nf < 2; ++nf) {
      const bf16* p = lds + cb + 16384 + nh * 8192 + (wc * 32 + nf * 16 + lr) * 64;
      bF[nh][nf][0] = *(const bf16x8*)(p + slot0);
      bF[nh][nf][1] = *(const bf16x8*)(p + (slot0 ^ 32));
    }
  };
  auto QUAD = [&](int H, int NH) {
#pragma unroll
    for (int kh = 0; kh < 2; ++kh)
#pragma unroll
      for (int mf = 0; mf < 4; ++mf)
#pragma unroll
        for (int nf = 0; nf < 2; ++nf)
          acc[H * 4 + mf][NH * 2 + nf] = __builtin_amdgcn_mfma_f32_16x16x32_bf16(
              aF[mf][kh], bF[NH][nf][kh], acc[H * 4 + mf][NH * 2 + nf], 0, 0, 0);
  };

#define MID(Q1, Q2)                          \
  __builtin_amdgcn_s_barrier();              \
  LGKM0;                                     \
  __builtin_amdgcn_sched_barrier(0);         \
  __builtin_amdgcn_s_setprio(1);             \
  QUAD(Q1, Q2);                              \
  __builtin_amdgcn_s_setprio(0);             \
  __builtin_amdgcn_s_barrier();

  // ---- prologue: stage tile 0 (seg0,kc0: A=Xhi, B=Whi), order Ah0,Bh0,Bh1,Ah1
  STAGE(Ahi, 0);
  STAGE(Whi, 16384);
  STAGE(Whi + 131072, 16384 + 8192);
  STAGE(Ahi + 131072, 8192);
  VMCNT(4);
  __builtin_amdgcn_s_barrier();

  int segN = 1, kcN = 0;  // next tile (kt+1)
  for (int kt = 0; kt < 47; ++kt) {
    const int cb = (kt & 1) * 32768, cnb = cb ^ 32768;
    const bf16* An = (segN == 2) ? Alo : Ahi;
    const bf16* Bn = (segN == 1) ? Wlo : Whi;
    const int kinN = kcN * 64;
    // phase 0: compute (Ah0,Bh0), stage next.Ah0
    READ_A(cb, 0);
    READ_B(cb, 0);
    STAGE(An + kinN, cnb);
    VMCNT(4);
    MID(0, 0)
    // phase 1: compute (Ah0,Bh1), stage next.Bh0
    READ_B(cb, 1);
    STAGE(Bn + kinN, cnb + 16384);
    VMCNT(4);
    MID(0, 1)
    // phase 2: compute (Ah1,Bh0), stage next.Bh1
    READ_A(cb, 1);
    STAGE(Bn + kinN + 131072, cnb + 16384 + 8192);
    VMCNT(4);
    MID(1, 0)
    // phase 3: compute (Ah1,Bh1), stage next.Ah1
    STAGE(An + kinN + 131072, cnb + 8192);
    VMCNT(4);
    MID(1, 1)
    if (++segN == 3) { segN = 0; ++kcN; }
  }
  // ---- epilogue tile 47 (buf cb = 32768), drain 2 -> 0
  {
    const int cb = 32768;
    READ_A(cb, 0);
    READ_B(cb, 0);
    VMCNT(2);
    MID(0, 0)
    READ_B(cb, 1);
    VMCNT(0);
    MID(0, 1)
    READ_A(cb, 1);
    MID(1, 0)
    __builtin_amdgcn_s_setprio(1);
    QUAD(1, 1);
    __builtin_amdgcn_s_setprio(0);
  }

  // ---- C write + bias
  const float* bias = (proj == 0) ? bk : (proj == 1 ? bq : bv);
  float* Out = (proj == 0) ? K : (proj == 1 ? Q : V);
#pragma unroll
  for (int jn = 0; jn < 4; ++jn) {
    const int nh = jn >> 1, nf2 = jn & 1;
    const int ccol = wn0 + nh * 128 + wc * 32 + nf2 * 16 + lr;
    const float bb = bias[ccol];
#pragma unroll
    for (int im = 0; im < 8; ++im) {
      const int h = im >> 2, mf = im & 3;
      const int row0 = gm0 + h * 128 + wr * 64 + mf * 16 + lk * 4;
#pragma unroll
      for (int r = 0; r < 4; ++r)
        Out[(size_t)(row0 + r) * 512 + ccol] = acc[im][jn][r] + bb;
    }
  }
}

// ---------------------------------------------------------------------------
// logits: AW[b,t,s] = (1/sqrt(512)) * sum_c K[b*64+t,c] * Q[b*64+s,c]
// pad 68 -> 16B-aligned rows for ds_read_b128 fragment loads.
// ---------------------------------------------------------------------------
__global__ __launch_bounds__(256) void logits_kernel(
    const float* __restrict__ K, const float* __restrict__ Q,
    float* __restrict__ AW) {
  __shared__ float Ks[64][68];  // [cc][t]
  __shared__ float Qs[64][68];  // [cc][s]
  const int b = blockIdx.x;
  const float* Kb = K + (size_t)b * 32768;
  const float* Qb = Q + (size_t)b * 32768;
  const int tid = threadIdx.x;
  const int tr = tid >> 4, tc = tid & 15;

  float acc[4][4] = {};
  for (int c0 = 0; c0 < 512; c0 += 64) {
    __syncthreads();
#pragma unroll
    for (int i = 0; i < 4; ++i) {
      int idx = tid + i * 256;
      int row = idx >> 4;
      int c4 = (idx & 15) * 4;
      float4 kv = *(const float4*)&Kb[row * 512 + c0 + c4];
      float4 qv = *(const float4*)&Qb[row * 512 + c0 + c4];
      Ks[c4 + 0][row] = kv.x; Ks[c4 + 1][row] = kv.y;
      Ks[c4 + 2][row] = kv.z; Ks[c4 + 3][row] = kv.w;
      Qs[c4 + 0][row] = qv.x; Qs[c4 + 1][row] = qv.y;
      Qs[c4 + 2][row] = qv.z; Qs[c4 + 3][row] = qv.w;
    }
    __syncthreads();
#pragma unroll 4
    for (int cc = 0; cc < 64; ++cc) {
      float4 kx = *(const float4*)&Ks[cc][tr * 4];
      float4 qx = *(const float4*)&Qs[cc][tc * 4];
#pragma unroll
      for (int i = 0; i < 4; ++i)
#pragma unroll
        for (int j = 0; j < 4; ++j) acc[i][j] += kx[i] * qx[j];
    }
  }
  const float scale = 0.04419417382415922f;  // 1/sqrt(512)
#pragma unroll
  for (int i = 0; i < 4; ++i)
#pragma unroll
    for (int j = 0; j < 4; ++j)
      AW[(size_t)b * 4096 + (tr * 4 + i) * 64 + (tc * 4 + j)] =
          acc[i][j] * scale;
}

// ---------------------------------------------------------------------------
__global__ __launch_bounds__(256) void softmax_kernel(float* __restrict__ AW) {
  __shared__ float red[4][64];
  const int tt = blockIdx.x;
  const int tid = threadIdx.x;
  const int s = tid & 63, bq = tid >> 6;
  const size_t base = (size_t)tt * 64 + s;

  float m = -3.4e38f;
  for (int b = bq * 128; b < bq * 128 + 128; ++b)
    m = fmaxf(m, AW[(size_t)b * 4096 + base]);
  red[bq][s] = m;
  __syncthreads();
  m = fmaxf(fmaxf(red[0][s], red[1][s]), fmaxf(red[2][s], red[3][s]));
  __syncthreads();

  float sum = 0.f;
  for (int b = bq * 128; b < bq * 128 + 128; ++b)
    sum += __expf(AW[(size_t)b * 4096 + base] - m);
  red[bq][s] = sum;
  __syncthreads();
  sum = red[0][s] + red[1][s] + red[2][s] + red[3][s];
  const float inv = 1.0f / sum;

  for (int b = bq * 128; b < bq * 128 + 128; ++b) {
    size_t o = (size_t)b * 4096 + base;
    AW[o] = __expf(AW[o] - m) * inv;
  }
}

// ---------------------------------------------------------------------------
// out[b,c,s] = sum_t V[b*64+t, c] * P[b,t,s].  V chunk staged in LDS
// (coalesced), broadcast reads in compute; stores coalesced over s.
// ---------------------------------------------------------------------------
__global__ __launch_bounds__(256) void out_kernel(
    const float* __restrict__ V, const float* __restrict__ AW,
    float* __restrict__ out) {
  __shared__ float Ps[64][68];
  __shared__ float Vs[64][68];  // [t][cc]
  const int b = blockIdx.x;
  const int tid = threadIdx.x;
  const float* Pb = AW + (size_t)b * 4096;
  for (int i = tid; i < 4096; i += 256) Ps[i >> 6][i & 63] = Pb[i];

  const int s = tid & 63, cw = tid >> 6;
  const float* Vb = V + (size_t)b * 32768;
  float* Ob = out + (size_t)b * 32768;

  for (int ch = 0; ch < 8; ++ch) {
    __syncthreads();
    for (int i = tid; i < 1024; i += 256) {
      int row = i >> 4, c4 = (i & 15) * 4;
      float4 v = *(const float4*)&Vb[(size_t)row * 512 + ch * 64 + c4];
      Vs[row][c4 + 0] = v.x; Vs[row][c4 + 1] = v.y;
      Vs[row][c4 + 2] = v.z; Vs[row][c4 + 3] = v.w;
    }
    __syncthreads();
    float a[16] = {};
    for (int t = 0; t < 64; ++t) {
      float p = Ps[t][s];
      float4 v0 = *(const float4*)&Vs[t][cw * 16 + 0];
      float4 v1 = *(const float4*)&Vs[t][cw * 16 + 4];
      float4 v2 = *(const float4*)&Vs[t][cw * 16 + 8];
      float4 v3 = *(const float4*)&Vs[t][cw * 16 + 12];
#pragma unroll
      for (int j = 0; j < 4; ++j) {
        a[j + 0] += v0[j] * p; a[j + 4] += v1[j] * p;
        a[j + 8] += v2[j] * p; a[j + 12] += v3[j] * p;
      }
    }
#pragma unroll
    for (int j = 0; j < 16; ++j)
      Ob[(size_t)(ch * 64 + cw * 16 + j) * 64 + s] = a[j];
  }
}

// ---------------------------------------------------------------------------
extern "C" void kernel_launch(void* const* d_in, const int* in_sizes, int n_in,
                              void* d_out, int out_size, void* d_ws,
                              size_t ws_size, hipStream_t stream) {
  const float* x  = (const float*)d_in[0];
  const float* Wk = (const float*)d_in[1];
  const float* bk = (const float*)d_in[2];
  const float* Wq = (const float*)d_in[3];
  const float* bq = (const float*)d_in[4];
  const float* Wv = (const float*)d_in[5];
  const float* bv = (const float*)d_in[6];
  float* out = (float*)d_out;

  char* ws = (char*)d_ws;
  bf16* Xhi = (bf16*)(ws + OFF_XHI);
  bf16* Xlo = (bf16*)(ws + OFF_XLO);
  bf16* WB  = (bf16*)(ws + OFF_WSP);
  float* K  = (float*)(ws + OFF_K);
  float* Q  = (float*)(ws + OFF_Q);
  float* V  = (float*)(ws + OFF_V);
  float* AW = (float*)(ws + OFF_AW);

  split_kernel<<<2048, 256, 0, stream>>>(x, Xhi, Xlo, 33554432 / 4);
  split_kernel<<<256, 256, 0, stream>>>(Wk, WB + 0ul * 1048576ul,
                                        WB + 0ul * 1048576ul + 524288ul,
                                        524288 / 4);
  split_kernel<<<256, 256, 0, stream>>>(Wq, WB + 1ul * 1048576ul,
                                        WB + 1ul * 1048576ul + 524288ul,
                                        524288 / 4);
  split_kernel<<<256, 256, 0, stream>>>(Wv, WB + 2ul * 1048576ul,
                                        WB + 2ul * 1048576ul + 524288ul,
                                        524288 / 4);

  gemm_kqv8<<<768, 512, 0, stream>>>(Xhi, Xlo, WB, bk, bq, bv, K, Q, V);

  logits_kernel<<<BATCH, 256, 0, stream>>>(K, Q, AW);
  softmax_kernel<<<NT, 256, 0, stream>>>(AW);
  out_kernel<<<BATCH, 256, 0, stream>>>(V, AW, out);
}

// Round 3
// 353.836 us; speedup vs baseline: 1.8487x; 1.3176x over previous
//
#include <hip/hip_runtime.h>
#include <hip/hip_bf16.h>

// ---------------------------------------------------------------------------
// TileSelfAttention, round 3.
// QKV GEMM via dual-digit int8 MFMA (exact i32 accumulation):
//   x ~= XS*(128*qh + ql), W ~= WS*(128*ph + pl)  (15-bit each)
//   x.W = XS*WS*(16384*acc1 + 128*acc2),  acc1 = qh.ph, acc2 = qh.pl + ql.ph
//   (ql.pl dropped, ~3e-5). i8 MFMA K=64 at 2x bf16 rate, half the bytes.
// 4-buffer depth-3 pipeline, per-phase counted vmcnt, register operand reuse.
// ---------------------------------------------------------------------------

typedef __bf16 bf16;
using i32x4 = __attribute__((ext_vector_type(4))) int;

#define NT     64
#define BATCH  512

// workspace byte offsets (~280 MB)
#define OFF_XQH 0ul
#define OFF_XQL 33554432ul
#define OFF_WQH 67108864ul
#define OFF_WQL 68681728ul
#define OFF_K   70254592ul
#define OFF_Q   137363456ul
#define OFF_V   204472320ul
#define OFF_AW  271581184ul

// ---------------------------------------------------------------------------
// quantize: fp32 -> (qh, ql) int8 digit planes.  q = clamp(rn(x*invS)),
// qh = (q+64)>>7 in [-127,127], ql = q - 128*qh in [-64,63].
// ---------------------------------------------------------------------------
__global__ void quant_kernel(const float* __restrict__ x,
                             unsigned int* __restrict__ qh,
                             unsigned int* __restrict__ ql, int n4, float invS) {
  int i = blockIdx.x * blockDim.x + threadIdx.x;
  int stride = gridDim.x * blockDim.x;
  for (; i < n4; i += stride) {
    float4 v = ((const float4*)x)[i];
    unsigned hw = 0, lw = 0;
#pragma unroll
    for (int j = 0; j < 4; ++j) {
      float f = (j == 0) ? v.x : (j == 1) ? v.y : (j == 2) ? v.z : v.w;
      int q = __float2int_rn(f * invS);
      q = max(-16320, min(16319, q));
      int h = (q + 64) >> 7;
      int lo = q - (h << 7);
      hw |= ((unsigned)(h & 0xFF)) << (8 * j);
      lw |= ((unsigned)(lo & 0xFF)) << (8 * j);
    }
    qh[i] = hw;
    ql[i] = lw;
  }
}

// ---------------------------------------------------------------------------
// i8 GEMM. Block tile 128(M) x 256(N), BK=64, 8 waves (2M x 4N), wave 64x64.
// LDS: 4 buffers x 24576 B  (A 128x64 i8 @0, B 256x64 i8 @8192).
// Swizzle: LDS slot s' holds global slot s'^f(row), f(r)=(r&3)^((r>>2)&3)
//   -> uniform bank spread for both staging (linear dst, pre-swz src) and
//      ds_read_b128 frag reads (read slot lk^f(row)).
// Pipeline: stage at phase p fills buffer (p+3)&3. Per-kc seg order
//   alpha(qh.pl->acc2), beta(qh.ph->acc1, A-frags reused), gamma(ql.ph->acc2,
//   B-frags reused). Stage counts 3/2/1 -> vmcnt 4/5/3.
// ---------------------------------------------------------------------------
__device__ __forceinline__ void gl16(const char* g, char* l) {
  __builtin_amdgcn_global_load_lds(
      (const __attribute__((address_space(1))) unsigned int*)g,
      (__attribute__((address_space(3))) unsigned int*)l, 16, 0, 0);
}

#define VMCNT(n) asm volatile("s_waitcnt vmcnt(" #n ")" ::: "memory")
#define LGKM0    asm volatile("s_waitcnt lgkmcnt(0)" ::: "memory")
#define BAR      __builtin_amdgcn_s_barrier()
#define FEN      LGKM0; __builtin_amdgcn_sched_barrier(0)

__global__ __launch_bounds__(512, 2) void gemm_i8(
    const char* __restrict__ XQH, const char* __restrict__ XQL,
    const char* __restrict__ WQH, const char* __restrict__ WQL,
    const float* __restrict__ bk, const float* __restrict__ bq,
    const float* __restrict__ bv,
    float* __restrict__ K, float* __restrict__ Q, float* __restrict__ V) {
  __shared__ __align__(16) char lds[98304];

  // bijective XCD swizzle: 1536 = 8 * 192
  const int bid = (blockIdx.x & 7) * 192 + (blockIdx.x >> 3);
  const int mt = bid / 6, ntb = bid % 6;
  const int gm0 = mt * 128;
  const int proj = ntb >> 1;
  const int wn0 = (ntb & 1) * 256;

  const int tid = threadIdx.x;
  const int l = tid & 63, w = tid >> 6;
  const int wr = w >> 2, wc = w & 3;  // 2M x 4N waves
  const int lr = l & 15, lk = l >> 4;
  const int fR = (lr & 3) ^ ((lr >> 2) & 3);
  const int rdA = (wr * 64 + lr) * 64 + ((lk ^ fR) * 16);
  const int rdB = 8192 + (wc * 64 + lr) * 64 + ((lk ^ fR) * 16);

  // staging lane constants (linear LDS dst, pre-swizzled global src)
  const int sRow = tid >> 2, sSlot = tid & 3;
  const int fS = (sRow & 3) ^ ((sRow >> 2) & 3);
  const size_t srcO = (size_t)sRow * 1024 + ((sSlot ^ fS) * 16);
  const int dstA = tid * 16;
  const int dstB1 = 8192 + tid * 16, dstB2 = 16384 + tid * 16;

  const char* Aqh = XQH + (size_t)gm0 * 1024;
  const char* Aql = XQL + (size_t)gm0 * 1024;
  const char* Bph = WQH + (size_t)proj * 524288 + (size_t)wn0 * 1024;
  const char* Bpl = WQL + (size_t)proj * 524288 + (size_t)wn0 * 1024;

  i32x4 acc1[4][4] = {};
  i32x4 acc2[4][4] = {};
  i32x4 aF[4], bF[4];

  auto SA = [&](const char* base, int kB, int buf) {
    gl16(base + kB + srcO, lds + buf * 24576 + dstA);
  };
  auto SB = [&](const char* base, int kB, int buf) {
    gl16(base + kB + srcO, lds + buf * 24576 + dstB1);
    gl16(base + kB + srcO + 131072, lds + buf * 24576 + dstB2);
  };
  auto RA = [&](int buf) {
#pragma unroll
    for (int mf = 0; mf < 4; ++mf)
      aF[mf] = *(const i32x4*)(lds + buf * 24576 + rdA + mf * 1024);
  };
  auto RB = [&](int buf) {
#pragma unroll
    for (int nf = 0; nf < 4; ++nf)
      bF[nf] = *(const i32x4*)(lds + buf * 24576 + rdB + nf * 1024);
  };
  auto MM = [&](i32x4(&acc)[4][4]) {
    __builtin_amdgcn_s_setprio(1);
#pragma unroll
    for (int mf = 0; mf < 4; ++mf)
#pragma unroll
      for (int nf = 0; nf < 4; ++nf)
        acc[mf][nf] = __builtin_amdgcn_mfma_i32_16x16x64_i8(aF[mf], bF[nf],
                                                            acc[mf][nf], 0, 0, 0);
    __builtin_amdgcn_s_setprio(0);
  };

#define P_ALPHA(B, KO)                              \
  RA(B); RB(B);                                     \
  SA(Aqh, kS + (KO), ((B) + 3) & 3);                \
  SB(Bpl, kS + (KO), ((B) + 3) & 3);                \
  VMCNT(4); BAR; FEN; MM(acc2); BAR;
#define P_BETA(B, KO)                               \
  RB(B);                                            \
  SB(Bph, kS + (KO), ((B) + 3) & 3);                \
  VMCNT(5); BAR; FEN; MM(acc1); BAR;
#define P_GAMMA(B, KO)                              \
  RA(B);                                            \
  SA(Aql, kS + (KO), ((B) + 3) & 3);                \
  VMCNT(3); BAR; FEN; MM(acc2); BAR;

  // prologue: buffers for phases 0,1,2 (kc 0)
  SA(Aqh, 0, 0);
  SB(Bpl, 0, 0);
  SB(Bph, 0, 1);
  SA(Aql, 0, 2);
  VMCNT(3);
  BAR;

  int kS = 0;
  for (int i = 0; i < 3; ++i) {
    P_ALPHA(0, 64)  P_BETA(1, 64)  P_GAMMA(2, 64)
    P_ALPHA(3, 128) P_BETA(0, 128) P_GAMMA(1, 128)
    P_ALPHA(2, 192) P_BETA(3, 192) P_GAMMA(0, 192)
    P_ALPHA(1, 256) P_BETA(2, 256) P_GAMMA(3, 256)
    kS += 256;
  }
  // tail iteration (kc 12..15), staging stops at phase 44
  P_ALPHA(0, 64)  P_BETA(1, 64)  P_GAMMA(2, 64)
  P_ALPHA(3, 128) P_BETA(0, 128) P_GAMMA(1, 128)
  P_ALPHA(2, 192) P_BETA(3, 192) P_GAMMA(0, 192)
  // p45 (alpha, buf1): need p43 stage done -> outstanding <= p44's 1 load
  RA(1); RB(1); VMCNT(1); BAR; FEN; MM(acc2); BAR;
  // p46 (beta, buf2): need p44 stage done -> vmcnt(0)
  RB(2); VMCNT(0); BAR; FEN; MM(acc1); BAR;
  // p47 (gamma, buf3)
  RA(3); BAR; FEN; MM(acc2); BAR;

  // epilogue: Out = XS*WS*(16384*acc1 + 128*acc2) + bias
  const float SC = (6.0f / 16256.0f) * (0.03125f / 16320.0f);
  const float* bias = (proj == 0) ? bk : (proj == 1 ? bq : bv);
  float* Out = (proj == 0) ? K : (proj == 1 ? Q : V);
#pragma unroll
  for (int mf = 0; mf < 4; ++mf) {
    const int row0 = gm0 + wr * 64 + mf * 16 + lk * 4;
#pragma unroll
    for (int nf = 0; nf < 4; ++nf) {
      const int col = wn0 + wc * 64 + nf * 16 + lr;
      const float bb = bias[col];
#pragma unroll
      for (int r = 0; r < 4; ++r)
        Out[(size_t)(row0 + r) * 512 + col] =
            fmaf(16384.f, (float)acc1[mf][nf][r],
                 128.f * (float)acc2[mf][nf][r]) * SC + bb;
    }
  }
}

// ---------------------------------------------------------------------------
// logits: AW[b,t,s] = (1/sqrt(512)) * sum_c K[b*64+t,c] * Q[b*64+s,c]
// ---------------------------------------------------------------------------
__global__ __launch_bounds__(256) void logits_kernel(
    const float* __restrict__ K, const float* __restrict__ Q,
    float* __restrict__ AW) {
  __shared__ float Ks[64][68];
  __shared__ float Qs[64][68];
  const int b = blockIdx.x;
  const float* Kb = K + (size_t)b * 32768;
  const float* Qb = Q + (size_t)b * 32768;
  const int tid = threadIdx.x;
  const int tr = tid >> 4, tc = tid & 15;

  float acc[4][4] = {};
  for (int c0 = 0; c0 < 512; c0 += 64) {
    __syncthreads();
#pragma unroll
    for (int i = 0; i < 4; ++i) {
      int idx = tid + i * 256;
      int row = idx >> 4;
      int c4 = (idx & 15) * 4;
      float4 kv = *(const float4*)&Kb[row * 512 + c0 + c4];
      float4 qv = *(const float4*)&Qb[row * 512 + c0 + c4];
      Ks[c4 + 0][row] = kv.x; Ks[c4 + 1][row] = kv.y;
      Ks[c4 + 2][row] = kv.z; Ks[c4 + 3][row] = kv.w;
      Qs[c4 + 0][row] = qv.x; Qs[c4 + 1][row] = qv.y;
      Qs[c4 + 2][row] = qv.z; Qs[c4 + 3][row] = qv.w;
    }
    __syncthreads();
#pragma unroll 4
    for (int cc = 0; cc < 64; ++cc) {
      float4 kx = *(const float4*)&Ks[cc][tr * 4];
      float4 qx = *(const float4*)&Qs[cc][tc * 4];
#pragma unroll
      for (int i = 0; i < 4; ++i)
#pragma unroll
        for (int j = 0; j < 4; ++j) acc[i][j] += kx[i] * qx[j];
    }
  }
  const float scale = 0.04419417382415922f;
#pragma unroll
  for (int i = 0; i < 4; ++i)
#pragma unroll
    for (int j = 0; j < 4; ++j)
      AW[(size_t)b * 4096 + (tr * 4 + i) * 64 + (tc * 4 + j)] =
          acc[i][j] * scale;
}

// ---------------------------------------------------------------------------
__global__ __launch_bounds__(256) void softmax_kernel(float* __restrict__ AW) {
  __shared__ float red[4][64];
  const int tt = blockIdx.x;
  const int tid = threadIdx.x;
  const int s = tid & 63, bq = tid >> 6;
  const size_t base = (size_t)tt * 64 + s;

  float m = -3.4e38f;
  for (int b = bq * 128; b < bq * 128 + 128; ++b)
    m = fmaxf(m, AW[(size_t)b * 4096 + base]);
  red[bq][s] = m;
  __syncthreads();
  m = fmaxf(fmaxf(red[0][s], red[1][s]), fmaxf(red[2][s], red[3][s]));
  __syncthreads();

  float sum = 0.f;
  for (int b = bq * 128; b < bq * 128 + 128; ++b)
    sum += __expf(AW[(size_t)b * 4096 + base] - m);
  red[bq][s] = sum;
  __syncthreads();
  sum = red[0][s] + red[1][s] + red[2][s] + red[3][s];
  const float inv = 1.0f / sum;

  for (int b = bq * 128; b < bq * 128 + 128; ++b) {
    size_t o = (size_t)b * 4096 + base;
    AW[o] = __expf(AW[o] - m) * inv;
  }
}

// ---------------------------------------------------------------------------
// out[b,c,s] = sum_t V[b*64+t, c] * P[b,t,s]
// ---------------------------------------------------------------------------
__global__ __launch_bounds__(256) void out_kernel(
    const float* __restrict__ V, const float* __restrict__ AW,
    float* __restrict__ out) {
  __shared__ float Ps[64][68];
  __shared__ float Vs[64][68];
  const int b = blockIdx.x;
  const int tid = threadIdx.x;
  const float* Pb = AW + (size_t)b * 4096;
  for (int i = tid; i < 4096; i += 256) Ps[i >> 6][i & 63] = Pb[i];

  const int s = tid & 63, cw = tid >> 6;
  const float* Vb = V + (size_t)b * 32768;
  float* Ob = out + (size_t)b * 32768;

  for (int ch = 0; ch < 8; ++ch) {
    __syncthreads();
    for (int i = tid; i < 1024; i += 256) {
      int row = i >> 4, c4 = (i & 15) * 4;
      float4 v = *(const float4*)&Vb[(size_t)row * 512 + ch * 64 + c4];
      Vs[row][c4 + 0] = v.x; Vs[row][c4 + 1] = v.y;
      Vs[row][c4 + 2] = v.z; Vs[row][c4 + 3] = v.w;
    }
    __syncthreads();
    float a[16] = {};
    for (int t = 0; t < 64; ++t) {
      float p = Ps[t][s];
      float4 v0 = *(const float4*)&Vs[t][cw * 16 + 0];
      float4 v1 = *(const float4*)&Vs[t][cw * 16 + 4];
      float4 v2 = *(const float4*)&Vs[t][cw * 16 + 8];
      float4 v3 = *(const float4*)&Vs[t][cw * 16 + 12];
#pragma unroll
      for (int j = 0; j < 4; ++j) {
        a[j + 0] += v0[j] * p; a[j + 4] += v1[j] * p;
        a[j + 8] += v2[j] * p; a[j + 12] += v3[j] * p;
      }
    }
#pragma unroll
    for (int j = 0; j < 16; ++j)
      Ob[(size_t)(ch * 64 + cw * 16 + j) * 64 + s] = a[j];
  }
}

// ---------------------------------------------------------------------------
extern "C" void kernel_launch(void* const* d_in, const int* in_sizes, int n_in,
                              void* d_out, int out_size, void* d_ws,
                              size_t ws_size, hipStream_t stream) {
  const float* x  = (const float*)d_in[0];
  const float* Wk = (const float*)d_in[1];
  const float* bk = (const float*)d_in[2];
  const float* Wq = (const float*)d_in[3];
  const float* bq = (const float*)d_in[4];
  const float* Wv = (const float*)d_in[5];
  const float* bv = (const float*)d_in[6];
  float* out = (float*)d_out;

  char* ws = (char*)d_ws;
  unsigned int* XQH = (unsigned int*)(ws + OFF_XQH);
  unsigned int* XQL = (unsigned int*)(ws + OFF_XQL);
  unsigned int* WQH = (unsigned int*)(ws + OFF_WQH);
  unsigned int* WQL = (unsigned int*)(ws + OFF_WQL);
  float* K  = (float*)(ws + OFF_K);
  float* Q  = (float*)(ws + OFF_Q);
  float* V  = (float*)(ws + OFF_V);
  float* AW = (float*)(ws + OFF_AW);

  const float invXS = 16256.0f / 6.0f;
  const float invWS = 16320.0f / 0.03125f;

  quant_kernel<<<2048, 256, 0, stream>>>(x, XQH, XQL, 8388608, invXS);
  quant_kernel<<<512, 256, 0, stream>>>(Wk, WQH, WQL, 131072, invWS);
  quant_kernel<<<512, 256, 0, stream>>>(Wq, WQH + 131072, WQL + 131072, 131072, invWS);
  quant_kernel<<<512, 256, 0, stream>>>(Wv, WQH + 262144, WQL + 262144, 131072, invWS);

  gemm_i8<<<1536, 512, 0, stream>>>((const char*)XQH, (const char*)XQL,
                                    (const char*)WQH, (const char*)WQL,
                                    bk, bq, bv, K, Q, V);

  logits_kernel<<<BATCH, 256, 0, stream>>>(K, Q, AW);
  softmax_kernel<<<NT, 256, 0, stream>>>(AW);
  out_kernel<<<BATCH, 256, 0, stream>>>(V, AW, out);
}

// Round 4
// 343.606 us; speedup vs baseline: 1.9038x; 1.0298x over previous
//
#include <hip/hip_runtime.h>
#include <hip/hip_bf16.h>

// ---------------------------------------------------------------------------
// TileSelfAttention, round 4.
// QKV GEMM via dual-digit int8 MFMA (exact i32 accumulation), restructured:
//   ONE barrier + ONE vmcnt(0) per K=64 chunk (16 total), all reads+MFMA in
//   a single region so the compiler overlaps ds_read with MFMA via granular
//   lgkmcnt.  2 x 48KB LDS buffers, 6 global_load_lds(16B)/thread/chunk.
//   Swizzle slot^=row&3: exactly 8 lanes/bank-quad per ds_read_b128.
// ---------------------------------------------------------------------------

typedef __bf16 bf16;
using i32x4 = __attribute__((ext_vector_type(4))) int;

#define NT     64
#define BATCH  512

#define OFF_XQH 0ul
#define OFF_XQL 33554432ul
#define OFF_WQH 67108864ul
#define OFF_WQL 68681728ul
#define OFF_K   70254592ul
#define OFF_Q   137363456ul
#define OFF_V   204472320ul
#define OFF_AW  271581184ul

// ---------------------------------------------------------------------------
__global__ void quant_kernel(const float* __restrict__ x,
                             unsigned int* __restrict__ qh,
                             unsigned int* __restrict__ ql, int n4, float invS) {
  int i = blockIdx.x * blockDim.x + threadIdx.x;
  int stride = gridDim.x * blockDim.x;
  for (; i < n4; i += stride) {
    float4 v = ((const float4*)x)[i];
    unsigned hw = 0, lw = 0;
#pragma unroll
    for (int j = 0; j < 4; ++j) {
      float f = (j == 0) ? v.x : (j == 1) ? v.y : (j == 2) ? v.z : v.w;
      int q = __float2int_rn(f * invS);
      q = max(-16320, min(16319, q));
      int h = (q + 64) >> 7;
      int lo = q - (h << 7);
      hw |= ((unsigned)(h & 0xFF)) << (8 * j);
      lw |= ((unsigned)(lo & 0xFF)) << (8 * j);
    }
    qh[i] = hw;
    ql[i] = lw;
  }
}

// ---------------------------------------------------------------------------
__device__ __forceinline__ void gl16(const char* g, char* l) {
  __builtin_amdgcn_global_load_lds(
      (const __attribute__((address_space(1))) unsigned int*)g,
      (__attribute__((address_space(3))) unsigned int*)l, 16, 0, 0);
}

#define VMCNT0 asm volatile("s_waitcnt vmcnt(0)" ::: "memory")
#define BAR    __builtin_amdgcn_s_barrier()

__global__ __launch_bounds__(512, 2) void gemm_i8(
    const char* __restrict__ XQH, const char* __restrict__ XQL,
    const char* __restrict__ WQH, const char* __restrict__ WQL,
    const float* __restrict__ bk, const float* __restrict__ bq,
    const float* __restrict__ bv,
    float* __restrict__ K, float* __restrict__ Q, float* __restrict__ V) {
  __shared__ __align__(16) char lds[98304];  // 2 x 48KB

  // T1: bijective XCD swizzle (1536 = 8 * 192)
  const int bid = (blockIdx.x & 7) * 192 + (blockIdx.x >> 3);
  const int mt = bid / 6, ntb = bid % 6;
  const int gm0 = mt * 128;
  const int proj = ntb >> 1;
  const int wn0 = (ntb & 1) * 256;

  const int tid = threadIdx.x;
  const int l = tid & 63, w = tid >> 6;
  const int wr = w >> 2, wc = w & 3;  // 2M x 4N waves, wave tile 64x64
  const int lr = l & 15, lk = l >> 4;
  // frag read base: row=lr within 16-row group, slot = lk ^ (row&3)
  const int rbase = lr * 64 + ((lk ^ (lr & 3)) * 16);
  const int rdA = wr * 4096 + rbase;           // + plane(0/8192) + mf*1024
  const int rdB = 16384 + wc * 4096 + rbase;   // + plane(0/16384) + nf*1024

  // staging: linear LDS dst (tid*16), pre-swizzled global src
  const int sRow = tid >> 2;
  const size_t srcO = (size_t)sRow * 1024 + (((tid & 3) ^ (sRow & 3)) * 16);
  const size_t srcO2 = srcO + 131072;  // +128 rows (row&3 invariant)
  const int dA = tid * 16;

  const char* Aqh = XQH + (size_t)gm0 * 1024;
  const char* Aql = XQL + (size_t)gm0 * 1024;
  const char* Bph = WQH + (size_t)proj * 524288 + (size_t)wn0 * 1024;
  const char* Bpl = WQL + (size_t)proj * 524288 + (size_t)wn0 * 1024;

  i32x4 acc1[4][4] = {};
  i32x4 acc2[4][4] = {};

  auto STAGE6 = [&](int bo, int kB) {
    gl16(Aqh + kB + srcO, lds + bo + dA);
    gl16(Aql + kB + srcO, lds + bo + 8192 + dA);
    gl16(Bph + kB + srcO, lds + bo + 16384 + dA);
    gl16(Bph + kB + srcO2, lds + bo + 16384 + 8192 + dA);
    gl16(Bpl + kB + srcO, lds + bo + 32768 + dA);
    gl16(Bpl + kB + srcO2, lds + bo + 32768 + 8192 + dA);
  };

  // prologue: stage chunk 0 into buffer 0
  STAGE6(0, 0);

  for (int kc = 0; kc < 16; ++kc) {
    const int bo = (kc & 1) * 49152;
    VMCNT0;  // own stages from prev chunk done (issued ~1 chunk ago)
    BAR;     // => all waves' stages landed; prev-chunk reads all retired
    // stage next chunk into the other buffer (issued early, overlaps MFMA)
    if (kc < 15) STAGE6(bo ^ 49152, (kc + 1) * 64);

    i32x4 aH[4], aL[4], bH[4], bL[4];
#pragma unroll
    for (int mf = 0; mf < 4; ++mf)
      aH[mf] = *(const i32x4*)(lds + bo + rdA + mf * 1024);
#pragma unroll
    for (int nf = 0; nf < 4; ++nf)
      bL[nf] = *(const i32x4*)(lds + bo + 16384 + rdB + nf * 1024);

    __builtin_amdgcn_s_setprio(1);
#pragma unroll
    for (int mf = 0; mf < 4; ++mf)   // alpha: qh . pl -> acc2
#pragma unroll
      for (int nf = 0; nf < 4; ++nf)
        acc2[mf][nf] = __builtin_amdgcn_mfma_i32_16x16x64_i8(
            aH[mf], bL[nf], acc2[mf][nf], 0, 0, 0);
    __builtin_amdgcn_s_setprio(0);

#pragma unroll
    for (int nf = 0; nf < 4; ++nf)
      bH[nf] = *(const i32x4*)(lds + bo + rdB + nf * 1024);

    __builtin_amdgcn_s_setprio(1);
#pragma unroll
    for (int mf = 0; mf < 4; ++mf)   // beta: qh . ph -> acc1 (reuse aH)
#pragma unroll
      for (int nf = 0; nf < 4; ++nf)
        acc1[mf][nf] = __builtin_amdgcn_mfma_i32_16x16x64_i8(
            aH[mf], bH[nf], acc1[mf][nf], 0, 0, 0);
    __builtin_amdgcn_s_setprio(0);

#pragma unroll
    for (int mf = 0; mf < 4; ++mf)
      aL[mf] = *(const i32x4*)(lds + bo + 8192 + rdA + mf * 1024);

    __builtin_amdgcn_s_setprio(1);
#pragma unroll
    for (int mf = 0; mf < 4; ++mf)   // gamma: ql . ph -> acc2 (reuse bH)
#pragma unroll
      for (int nf = 0; nf < 4; ++nf)
        acc2[mf][nf] = __builtin_amdgcn_mfma_i32_16x16x64_i8(
            aL[mf], bH[nf], acc2[mf][nf], 0, 0, 0);
    __builtin_amdgcn_s_setprio(0);
  }

  // epilogue: Out = XS*WS*(16384*acc1 + 128*acc2) + bias
  const float SC = (6.0f / 16256.0f) * (0.03125f / 16320.0f);
  const float* bias = (proj == 0) ? bk : (proj == 1 ? bq : bv);
  float* Out = (proj == 0) ? K : (proj == 1 ? Q : V);
#pragma unroll
  for (int mf = 0; mf < 4; ++mf) {
    const int row0 = gm0 + wr * 64 + mf * 16 + lk * 4;
#pragma unroll
    for (int nf = 0; nf < 4; ++nf) {
      const int col = wn0 + wc * 64 + nf * 16 + lr;
      const float bb = bias[col];
#pragma unroll
      for (int r = 0; r < 4; ++r)
        Out[(size_t)(row0 + r) * 512 + col] =
            fmaf(16384.f, (float)acc1[mf][nf][r],
                 128.f * (float)acc2[mf][nf][r]) * SC + bb;
    }
  }
}

// ---------------------------------------------------------------------------
__global__ __launch_bounds__(256) void logits_kernel(
    const float* __restrict__ K, const float* __restrict__ Q,
    float* __restrict__ AW) {
  __shared__ float Ks[64][68];
  __shared__ float Qs[64][68];
  const int b = blockIdx.x;
  const float* Kb = K + (size_t)b * 32768;
  const float* Qb = Q + (size_t)b * 32768;
  const int tid = threadIdx.x;
  const int tr = tid >> 4, tc = tid & 15;

  float acc[4][4] = {};
  for (int c0 = 0; c0 < 512; c0 += 64) {
    __syncthreads();
#pragma unroll
    for (int i = 0; i < 4; ++i) {
      int idx = tid + i * 256;
      int row = idx >> 4;
      int c4 = (idx & 15) * 4;
      float4 kv = *(const float4*)&Kb[row * 512 + c0 + c4];
      float4 qv = *(const float4*)&Qb[row * 512 + c0 + c4];
      Ks[c4 + 0][row] = kv.x; Ks[c4 + 1][row] = kv.y;
      Ks[c4 + 2][row] = kv.z; Ks[c4 + 3][row] = kv.w;
      Qs[c4 + 0][row] = qv.x; Qs[c4 + 1][row] = qv.y;
      Qs[c4 + 2][row] = qv.z; Qs[c4 + 3][row] = qv.w;
    }
    __syncthreads();
#pragma unroll 4
    for (int cc = 0; cc < 64; ++cc) {
      float4 kx = *(const float4*)&Ks[cc][tr * 4];
      float4 qx = *(const float4*)&Qs[cc][tc * 4];
#pragma unroll
      for (int i = 0; i < 4; ++i)
#pragma unroll
        for (int j = 0; j < 4; ++j) acc[i][j] += kx[i] * qx[j];
    }
  }
  const float scale = 0.04419417382415922f;
#pragma unroll
  for (int i = 0; i < 4; ++i)
#pragma unroll
    for (int j = 0; j < 4; ++j)
      AW[(size_t)b * 4096 + (tr * 4 + i) * 64 + (tc * 4 + j)] =
          acc[i][j] * scale;
}

// ---------------------------------------------------------------------------
__global__ __launch_bounds__(256) void softmax_kernel(float* __restrict__ AW) {
  __shared__ float red[4][64];
  const int tt = blockIdx.x;
  const int tid = threadIdx.x;
  const int s = tid & 63, bq = tid >> 6;
  const size_t base = (size_t)tt * 64 + s;

  float m = -3.4e38f;
  for (int b = bq * 128; b < bq * 128 + 128; ++b)
    m = fmaxf(m, AW[(size_t)b * 4096 + base]);
  red[bq][s] = m;
  __syncthreads();
  m = fmaxf(fmaxf(red[0][s], red[1][s]), fmaxf(red[2][s], red[3][s]));
  __syncthreads();

  float sum = 0.f;
  for (int b = bq * 128; b < bq * 128 + 128; ++b)
    sum += __expf(AW[(size_t)b * 4096 + base] - m);
  red[bq][s] = sum;
  __syncthreads();
  sum = red[0][s] + red[1][s] + red[2][s] + red[3][s];
  const float inv = 1.0f / sum;

  for (int b = bq * 128; b < bq * 128 + 128; ++b) {
    size_t o = (size_t)b * 4096 + base;
    AW[o] = __expf(AW[o] - m) * inv;
  }
}

// ---------------------------------------------------------------------------
__global__ __launch_bounds__(256) void out_kernel(
    const float* __restrict__ V, const float* __restrict__ AW,
    float* __restrict__ out) {
  __shared__ float Ps[64][68];
  __shared__ float Vs[64][68];
  const int b = blockIdx.x;
  const int tid = threadIdx.x;
  const float* Pb = AW + (size_t)b * 4096;
  for (int i = tid; i < 4096; i += 256) Ps[i >> 6][i & 63] = Pb[i];

  const int s = tid & 63, cw = tid >> 6;
  const float* Vb = V + (size_t)b * 32768;
  float* Ob = out + (size_t)b * 32768;

  for (int ch = 0; ch < 8; ++ch) {
    __syncthreads();
    for (int i = tid; i < 1024; i += 256) {
      int row = i >> 4, c4 = (i & 15) * 4;
      float4 v = *(const float4*)&Vb[(size_t)row * 512 + ch * 64 + c4];
      Vs[row][c4 + 0] = v.x; Vs[row][c4 + 1] = v.y;
      Vs[row][c4 + 2] = v.z; Vs[row][c4 + 3] = v.w;
    }
    __syncthreads();
    float a[16] = {};
    for (int t = 0; t < 64; ++t) {
      float p = Ps[t][s];
      float4 v0 = *(const float4*)&Vs[t][cw * 16 + 0];
      float4 v1 = *(const float4*)&Vs[t][cw * 16 + 4];
      float4 v2 = *(const float4*)&Vs[t][cw * 16 + 8];
      float4 v3 = *(const float4*)&Vs[t][cw * 16 + 12];
#pragma unroll
      for (int j = 0; j < 4; ++j) {
        a[j + 0] += v0[j] * p; a[j + 4] += v1[j] * p;
        a[j + 8] += v2[j] * p; a[j + 12] += v3[j] * p;
      }
    }
#pragma unroll
    for (int j = 0; j < 16; ++j)
      Ob[(size_t)(ch * 64 + cw * 16 + j) * 64 + s] = a[j];
  }
}

// ---------------------------------------------------------------------------
extern "C" void kernel_launch(void* const* d_in, const int* in_sizes, int n_in,
                              void* d_out, int out_size, void* d_ws,
                              size_t ws_size, hipStream_t stream) {
  const float* x  = (const float*)d_in[0];
  const float* Wk = (const float*)d_in[1];
  const float* bk = (const float*)d_in[2];
  const float* Wq = (const float*)d_in[3];
  const float* bq = (const float*)d_in[4];
  const float* Wv = (const float*)d_in[5];
  const float* bv = (const float*)d_in[6];
  float* out = (float*)d_out;

  char* ws = (char*)d_ws;
  unsigned int* XQH = (unsigned int*)(ws + OFF_XQH);
  unsigned int* XQL = (unsigned int*)(ws + OFF_XQL);
  unsigned int* WQH = (unsigned int*)(ws + OFF_WQH);
  unsigned int* WQL = (unsigned int*)(ws + OFF_WQL);
  float* K  = (float*)(ws + OFF_K);
  float* Q  = (float*)(ws + OFF_Q);
  float* V  = (float*)(ws + OFF_V);
  float* AW = (float*)(ws + OFF_AW);

  const float invXS = 16256.0f / 6.0f;
  const float invWS = 16320.0f / 0.03125f;

  quant_kernel<<<2048, 256, 0, stream>>>(x, XQH, XQL, 8388608, invXS);
  quant_kernel<<<512, 256, 0, stream>>>(Wk, WQH, WQL, 131072, invWS);
  quant_kernel<<<512, 256, 0, stream>>>(Wq, WQH + 131072, WQL + 131072, 131072, invWS);
  quant_kernel<<<512, 256, 0, stream>>>(Wv, WQH + 262144, WQL + 262144, 131072, invWS);

  gemm_i8<<<1536, 512, 0, stream>>>((const char*)XQH, (const char*)XQL,
                                    (const char*)WQH, (const char*)WQL,
                                    bk, bq, bv, K, Q, V);

  logits_kernel<<<BATCH, 256, 0, stream>>>(K, Q, AW);
  softmax_kernel<<<NT, 256, 0, stream>>>(AW);
  out_kernel<<<BATCH, 256, 0, stream>>>(V, AW, out);
}